// Round 2
// baseline (476.302 us; speedup 1.0000x reference)
//
#include <hip/hip_runtime.h>
#include <hip/hip_bf16.h>
#include <stdint.h>

// Problem constants (from reference: N=4264, B=256, NG=8, GS=533, SAMPLE_NUM=10)
#define NN 4264
#define BB 256
#define GSZ 533
#define NGRP 8
#define NSWEEP 10
#define NSTEP (NSWEEP * NGRP)
#define DMAX 48   // exact-table cap (Poisson(15): P(deg>48) ~ 1e-11 per node)
#define NCOLD 24  // cold slots: neighbors NOT in previous color group (spill -> hot region)
#define NHOT 12   // hot slots: neighbors IN previous color group (must be read post-barrier)
#define NPACK 36  // words per node = NCOLD + NHOT (9 uint4 = 144 B)
#define NW 9      // uint4 words per node
#define NF4 1066  // NN/4 float4s per row (17056 B, 16B-aligned)
#define NIT 17    // ceil(NF4/64) float4-iterations per wave

struct Keys { unsigned k0[NSTEP]; unsigned k1[NSTEP]; };

// ---- threefry2x32, exactly as JAX (20 rounds, key injections every 4) ----
#define TF_ROUND(x0, x1, r) { x0 += x1; x1 = (x1 << (r)) | (x1 >> (32 - (r))); x1 ^= x0; }
#define TF_BODY(K0, K1, C0, C1, O0, O1) {                                   \
  unsigned ks0 = (K0), ks1 = (K1), ks2 = (K0) ^ (K1) ^ 0x1BD11BDAu;          \
  unsigned x0 = (C0) + ks0, x1 = (C1) + ks1;                                 \
  TF_ROUND(x0, x1, 13) TF_ROUND(x0, x1, 15) TF_ROUND(x0, x1, 26) TF_ROUND(x0, x1, 6)  \
  x0 += ks1; x1 += ks2 + 1u;                                                 \
  TF_ROUND(x0, x1, 17) TF_ROUND(x0, x1, 29) TF_ROUND(x0, x1, 16) TF_ROUND(x0, x1, 24) \
  x0 += ks2; x1 += ks0 + 2u;                                                 \
  TF_ROUND(x0, x1, 13) TF_ROUND(x0, x1, 15) TF_ROUND(x0, x1, 26) TF_ROUND(x0, x1, 6)  \
  x0 += ks0; x1 += ks1 + 3u;                                                 \
  TF_ROUND(x0, x1, 17) TF_ROUND(x0, x1, 29) TF_ROUND(x0, x1, 16) TF_ROUND(x0, x1, 24) \
  x0 += ks1; x1 += ks2 + 4u;                                                 \
  TF_ROUND(x0, x1, 13) TF_ROUND(x0, x1, 15) TF_ROUND(x0, x1, 26) TF_ROUND(x0, x1, 6)  \
  x0 += ks2; x1 += ks0 + 5u;                                                 \
  (O0) = x0; (O1) = x1; }

static void tf_host(unsigned k0, unsigned k1, unsigned c0, unsigned c1,
                    unsigned* o0, unsigned* o1) {
  unsigned a, b;
  TF_BODY(k0, k1, c0, c1, a, b);
  *o0 = a; *o1 = b;
}

__device__ __forceinline__ void tf_dev(unsigned k0, unsigned k1, unsigned c0, unsigned c1,
                                       unsigned& o0, unsigned& o1) {
  TF_BODY(k0, k1, c0, c1, o0, o1);
}

// r(step, c) = u*2-1 from the xor-fold of threefry2x32(key_step, (0, c)) — the
// jax.random.uniform (threefry_partitionable) stream. Exact in f32.
__device__ __forceinline__ float tf_r(unsigned k0, unsigned k1, unsigned c) {
  unsigned o0, o1;
  tf_dev(k0, k1, 0u, c, o0, o1);
  const unsigned bits = o0 ^ o1;
  const float u = __uint_as_float((bits >> 9) | 0x3f800000u) - 1.0f;
  return u * 2.0f - 1.0f;
}

// ---- Tiny kernel: node -> color-group inverse map ----
__global__ __launch_bounds__(256) void build_inv(const int* __restrict__ groups,
                                                 int* __restrict__ invg) {
  const int p = blockIdx.x * 256 + threadIdx.x;
  if (p < NN) invg[groups[p]] = p / GSZ;
}

// ---- Build tables: wave-per-row, full-row register prefetch, no barriers ----
// Row p = g*GSZ + i -> node = groups[p].  prevg = (g-1) mod 8.
// pack layout per node (NPACK=36 words, zero-padded):
//   slots [0,NCOLD):       cold entries (neighbor NOT in prevg), ascending col
//   slots [NCOLD,NPACK):   hot entries (neighbor IN prevg) ascending, then cold
//                          spill (cold rank >= NCOLD), then zero padding
// word = (bf16_rne(val) << 16) | (col << 2)  (low half = LDS byte offset of m[col])
// exact8[p*DMAX + k] = {col, f32 val} ascending — exact-fallback table.
// marg[p] = 2^-9 * sum|val| + 2e-5, or 1e30 ("bad": deg>NPACK or hot>NHOT ->
//           permanent exact path; P(any bad node) ~ 4e-3 for this graph).
__global__ __launch_bounds__(256) void build_ell(const float* __restrict__ J,
                                                 const int* __restrict__ groups,
                                                 const int* __restrict__ invg,
                                                 unsigned* __restrict__ pack,
                                                 int2* __restrict__ exact8,
                                                 int* __restrict__ deg,
                                                 float* __restrict__ marg) {
  __shared__ int2 scr[4][DMAX];  // per-wave compacted (col, valbits)
  const int wv = threadIdx.x >> 6, lane = threadIdx.x & 63;
  const int p = blockIdx.x * 4 + wv;
  if (p >= NN) return;
  const int node = groups[p];
  const int prevg = (p / GSZ + NGRP - 1) % NGRP;
  const float4* row = (const float4*)(J + (size_t)node * NN);

  // Phase 1: issue ALL row loads (17 KB/wave in flight -> BW-bound, not latency)
  float4 vv[NIT];
#pragma unroll
  for (int it = 0; it < NIT; ++it) {
    const int q = it * 64 + lane;
    vv[it] = (q < NF4) ? row[q] : make_float4(0.0f, 0.0f, 0.0f, 0.0f);
  }

  // Phase 2a: ballot compaction on registers (exact ascending-column order)
  int cnt = 0;
#pragma unroll
  for (int it = 0; it < NIT; ++it) {
    const float4 v = vv[it];
    const int c0 = (it * 64 + lane) * 4;
#define COMP(X, CIDX) {                                                        \
      const bool nz = ((X) != 0.0f);                                           \
      const unsigned long long mk = __ballot(nz);                              \
      const int rk = cnt + __popcll(mk & ((1ull << lane) - 1ull));             \
      if (nz && rk < DMAX) {                                                   \
        const int2 e = make_int2((CIDX), __float_as_int(X));                   \
        exact8[(size_t)p * DMAX + rk] = e;                                     \
        scr[wv][rk] = e;                                                       \
      }                                                                        \
      cnt += __popcll(mk); }
    COMP(v.x, c0 + 0) COMP(v.y, c0 + 1) COMP(v.z, c0 + 2) COMP(v.w, c0 + 3)
#undef COMP
  }

  // Phase 2b: classify hot/cold (same wave wrote scr -> in-order DS, no barrier)
  const int cl = (cnt < DMAX) ? cnt : DMAX;
  const bool vl = (lane < cl);
  int col = 0; float val = 0.0f;
  if (vl) { const int2 e = scr[wv][lane]; col = e.x; val = __int_as_float(e.y); }
  const bool hot = vl && (invg[col] == prevg);
  const unsigned long long hm = __ballot(hot);
  const int nH = __popcll(hm);
  const int rkH = __popcll(hm & ((1ull << lane) - 1ull));
  const bool bad = (cnt > NPACK) || (nH > NHOT);
  float asum = vl ? fabsf(val) : 0.0f;

  if (!bad) {
    if (vl) {
      const int rkC = lane - rkH;  // cold rank (ranks ascending by col per class)
      const int slot = hot ? (NCOLD + rkH)
                           : ((rkC < NCOLD) ? rkC : nH + rkC);  // spill after hot
      const unsigned bits = __float_as_uint(val);
      const unsigned bf = (bits + 0x7fffu + ((bits >> 16) & 1u)) >> 16;
      pack[(size_t)p * NPACK + slot] = (bf << 16) | ((unsigned)col << 2);
    }
    const int nC = cl - nH;
    const int cend = (nC < NCOLD) ? nC : NCOLD;           // cold region fill end
    const int hend = (nC > NCOLD) ? cl : (NCOLD + nH);    // hot region fill end
    for (int k = lane; k < NPACK; k += 64)
      if ((k >= cend && k < NCOLD) || (k >= hend))
        pack[(size_t)p * NPACK + k] = 0u;                 // disjoint from value slots
  } else {
    for (int k = lane; k < NPACK; k += 64) pack[(size_t)p * NPACK + k] = 0u;
  }

  for (int s = 1; s < 64; s <<= 1) asum += __shfl_xor(asum, s, 64);
  if (lane == 0) {
    deg[p] = cl;
    marg[p] = bad ? 1e30f : (asum * 0.001953125f + 2e-5f);  // 2^-9*sum|v| + slack
  }
}

// ---- Full Gibbs chain: one workgroup per batch row (rows are independent) ----
// 576 threads = 9 waves, one node per thread per group-step.
// Three register pipelines, all ahead of consumption:
//  - pack words (9 uint4) for step s+1, loaded at step s-1 (depth-2: needed at
//    TOP of step s for the cold pre-gather)
//  - cold partial sum for step s+1: neighbors not in group g are final during
//    step s (their groups were last written <= s-2), so ~87% of the gather is
//    pre-accumulated OFF the critical path, overlapping step-s tanh/barriers.
//    Cold addresses are disjoint from step-s writes (group g) -> race-free.
//  - r for step s+1 (threefry dependent chain retires in the step-s shadow)
// Post-barrier critical path: 12 hot LDS reads (avg 1.9 real + addr-0 padding
// broadcasts) + fold + tanhf + 2 barriers.
__global__ __launch_bounds__(576, 3) void gibbs(const float* __restrict__ m0,
                                                const float* __restrict__ H,
                                                const int* __restrict__ groups,
                                                const unsigned* __restrict__ pack,
                                                const int2* __restrict__ exact8,
                                                const int* __restrict__ deg,
                                                const float* __restrict__ marg,
                                                float* __restrict__ out,
                                                Keys keys) {
  __shared__ float m_lds[NN];
  const int b = blockIdx.x;
  const int i = threadIdx.x;
  const bool active = (i < GSZ);

  for (int n = i; n < NN; n += 576) m_lds[n] = m0[(size_t)b * NN + n];

  // Per-thread per-group preload (step-invariant).
  int nodeg[NGRP];
  float hg[NGRP], mgg[NGRP];
  int dgg[NGRP];
  if (active) {
#pragma unroll
    for (int g = 0; g < NGRP; ++g) {
      const int p = g * GSZ + i;
      nodeg[g] = groups[p];
      hg[g] = H[nodeg[g]];
      dgg[g] = deg[p];
      mgg[g] = marg[p];
    }
  }

  const unsigned c = (unsigned)(b * GSZ + i);

  // value = high-16 bits as f32 (bf16<<16); addr = low-16 = LDS byte offset
#define MV(W)  (*(const float*)((const char*)m_lds + ((W) & 0xFFFCu)))
#define ACC4(W, A0, A1, A2, A3)                                   \
  A0 += __uint_as_float((W).x & 0xFFFF0000u) * MV((W).x);         \
  A1 += __uint_as_float((W).y & 0xFFFF0000u) * MV((W).y);         \
  A2 += __uint_as_float((W).z & 0xFFFF0000u) * MV((W).z);         \
  A3 += __uint_as_float((W).w & 0xFFFF0000u) * MV((W).w);

  // Pipeline registers: h = hot(s) [3 uint4], cN = words(s+1) [9 uint4].
  uint4 c0, c1, c2, c3, c4, c5, c6, c7, c8;
  uint4 h0, h1, h2;
  uint4 p0, p1, p2, p3, p4, p5;
  float preSum = 0.0f, rcur = 0.0f;

  if (active) {
    const uint4* q0 = (const uint4*)(pack + (size_t)i * NPACK);          // group 0
    p0 = q0[0]; p1 = q0[1]; p2 = q0[2]; p3 = q0[3]; p4 = q0[4]; p5 = q0[5];
    h0 = q0[6]; h1 = q0[7]; h2 = q0[8];
    const uint4* q1 = (const uint4*)(pack + (size_t)(GSZ + i) * NPACK);  // group 1
    c0 = q1[0]; c1 = q1[1]; c2 = q1[2]; c3 = q1[3]; c4 = q1[4];
    c5 = q1[5]; c6 = q1[6]; c7 = q1[7]; c8 = q1[8];
    rcur = tf_r(keys.k0[0], keys.k1[0], c);
  }
  __syncthreads();  // m_lds ready
  if (active) {
    // Prime cold partial sum for step 0 (initial state == "values at step -1").
    float a0 = 0.0f, a1 = 0.0f, a2 = 0.0f, a3 = 0.0f;
    ACC4(p0, a0, a1, a2, a3) ACC4(p1, a0, a1, a2, a3) ACC4(p2, a0, a1, a2, a3)
    ACC4(p3, a0, a1, a2, a3) ACC4(p4, a0, a1, a2, a3) ACC4(p5, a0, a1, a2, a3)
    preSum = (a0 + a1) + (a2 + a3);
  }

#pragma unroll 1
  for (int t = 0; t < NSWEEP; ++t) {
#pragma unroll
    for (int g = 0; g < NGRP; ++g) {
      const int step = t * NGRP + g;
      float nv = 0.0f;
      uint4 n0, n1, n2, n3, n4, n5, n6, n7, n8;
      float rnext = 0.0f, npre = 0.0f;
      if (active) {
        // Prefetch words for step s+2 (depth-2 pipeline; consumed next rotate).
        {
          const int gn = (g + 2) & (NGRP - 1);
          const uint4* qn = (const uint4*)(pack + (size_t)(gn * GSZ + i) * NPACK);
          n0 = qn[0]; n1 = qn[1]; n2 = qn[2]; n3 = qn[3]; n4 = qn[4];
          n5 = qn[5]; n6 = qn[6]; n7 = qn[7]; n8 = qn[8];
        }
        // Next step's threefry: dependent chain retires under this step's work.
        {
          const int sn = (step + 1 < NSTEP) ? step + 1 : step;
          rnext = tf_r(keys.k0[sn], keys.k1[sn], c);
        }

        // Hot gather (critical path): 12 slots, padding reads m_lds[0] (bcast).
        float a0 = 0.0f, a1 = 0.0f, a2 = 0.0f, a3 = 0.0f;
        ACC4(h0, a0, a1, a2, a3) ACC4(h1, a0, a1, a2, a3) ACC4(h2, a0, a1, a2, a3)

        // Cold pre-gather for step s+1 (off critical path; addresses disjoint
        // from this step's write group g -> safe to read before/during writes).
        float b0 = 0.0f, b1 = 0.0f, b2 = 0.0f, b3 = 0.0f;
        ACC4(c0, b0, b1, b2, b3) ACC4(c1, b0, b1, b2, b3) ACC4(c2, b0, b1, b2, b3)
        ACC4(c3, b0, b1, b2, b3) ACC4(c4, b0, b1, b2, b3) ACC4(c5, b0, b1, b2, b3)

        const float I = preSum + ((a0 + a1) + (a2 + a3)) + hg[g];
        const float th = tanhf(I);
        const float d = th - rcur;
        if (__builtin_expect(fabsf(d) > mgg[g], 1)) {
          // |tanhf(I_fast) - tanh64(I_exact)| <= marg -> sign matches exact
          nv = (d > 0.0f) ? 1.0f : -1.0f;
        } else {
          // Boundary-close (or bad node): settle in f64 from exact f32 table.
          const int dg = dgg[g];
          const int2* ep = exact8 + (size_t)(g * GSZ + i) * DMAX;
          double I64 = (double)hg[g];
          for (int k = 0; k < dg; ++k) {
            const int2 e = ep[k];
            I64 += (double)__int_as_float(e.y) * (double)m_lds[e.x];
          }
          const double diff = tanh(I64) - (double)rcur;
          nv = (diff > 0.0) ? 1.0f : ((diff < 0.0) ? -1.0f : 0.0f);
        }
        npre = (b0 + b1) + (b2 + b3);
      }
      __syncthreads();                  // all gathers done
      if (active) m_lds[nodeg[g]] = nv; // compute-all-then-set semantics
      __syncthreads();                  // scatter visible before next hot gather
      if (active) {
        preSum = npre; rcur = rnext;
        h0 = c6; h1 = c7; h2 = c8;      // hot(s+1) carried from words(s+1)
        c0 = n0; c1 = n1; c2 = n2; c3 = n3; c4 = n4;
        c5 = n5; c6 = n6; c7 = n7; c8 = n8;
      }
    }
  }

  for (int n = i; n < NN; n += 576) out[(size_t)b * NN + n] = m_lds[n];
#undef ACC4
#undef MV
}

extern "C" void kernel_launch(void* const* d_in, const int* in_sizes, int n_in,
                              void* d_out, int out_size, void* d_ws, size_t ws_size,
                              hipStream_t stream) {
  const float* m0     = (const float*)d_in[0];
  const float* J      = (const float*)d_in[1];
  const float* H      = (const float*)d_in[2];
  const int*   groups = (const int*)d_in[3];
  // d_in[4] = sample_num (=10, hardcoded as NSWEEP)

  // Workspace: pack[NN*NPACK] u32 (614 KB) | exact8[NN*DMAX] int2 (1.64 MB)
  //          | deg[NN] i32 | marg[NN] f32 | invg[NN] i32   -> ~2.30 MB total
  char* ws = (char*)d_ws;
  unsigned* pack   = (unsigned*)ws;                     ws += (size_t)NN * NPACK * 4;
  int2*     exact8 = (int2*)ws;                         ws += (size_t)NN * DMAX * 8;
  int*      deg    = (int*)ws;                          ws += (size_t)NN * 4;
  float*    marg   = (float*)ws;                        ws += (size_t)NN * 4;
  int*      invg   = (int*)ws;

  // Host-side key schedule, jax_threefry_partitionable=True (fold-like split):
  // key(42) -> (0, 42); split(key, n)[i] = threefry2x32(key, (0, i)).
  Keys keys;
  for (int t = 0; t < NSWEEP; ++t) {
    unsigned ik0, ik1;
    tf_host(0u, 42u, 0u, (unsigned)t, &ik0, &ik1);
    for (int g = 0; g < NGRP; ++g) {
      unsigned gk0, gk1;
      tf_host(ik0, ik1, 0u, (unsigned)g, &gk0, &gk1);
      keys.k0[t * NGRP + g] = gk0;
      keys.k1[t * NGRP + g] = gk1;
    }
  }

  build_inv<<<(NN + 255) / 256, 256, 0, stream>>>(groups, invg);
  build_ell<<<(NN + 3) / 4, 256, 0, stream>>>(J, groups, invg, pack, exact8, deg, marg);
  gibbs<<<BB, 576, 0, stream>>>(m0, H, groups, pack, exact8, deg, marg,
                                (float*)d_out, keys);
}

// Round 4
// 337.327 us; speedup vs baseline: 1.4120x; 1.4120x over previous
//
#include <hip/hip_runtime.h>
#include <hip/hip_bf16.h>
#include <stdint.h>

// Problem constants (from reference: N=4264, B=256, NG=8, GS=533, SAMPLE_NUM=10)
#define NN 4264
#define BB 256
#define GSZ 533
#define NGRP 8
#define NSWEEP 10
#define NSTEP (NSWEEP * NGRP)
#define DMAX 48   // exact-table cap (Poisson(15): P(deg>48) ~ 1e-11 per node)
#define NCOLD 24  // cold slots: neighbors NOT in previous color group (spill -> hot region)
#define NHOT 12   // hot slots: neighbors IN previous color group (read post-barrier)
#define NPACK 36  // words per node = NCOLD + NHOT (9 uint4 = 144 B)
#define NF4 1066  // NN/4 float4s per row (17056 B, 16B-aligned)
#define NIT 17    // ceil(NF4/64) float4-iterations per wave

struct Keys { unsigned k0[NSTEP]; unsigned k1[NSTEP]; };

// ---- threefry2x32, exactly as JAX (20 rounds, key injections every 4) ----
#define TF_ROUND(x0, x1, r) { x0 += x1; x1 = (x1 << (r)) | (x1 >> (32 - (r))); x1 ^= x0; }
#define TF_BODY(K0, K1, C0, C1, O0, O1) {                                   \
  unsigned ks0 = (K0), ks1 = (K1), ks2 = (K0) ^ (K1) ^ 0x1BD11BDAu;          \
  unsigned x0 = (C0) + ks0, x1 = (C1) + ks1;                                 \
  TF_ROUND(x0, x1, 13) TF_ROUND(x0, x1, 15) TF_ROUND(x0, x1, 26) TF_ROUND(x0, x1, 6)  \
  x0 += ks1; x1 += ks2 + 1u;                                                 \
  TF_ROUND(x0, x1, 17) TF_ROUND(x0, x1, 29) TF_ROUND(x0, x1, 16) TF_ROUND(x0, x1, 24) \
  x0 += ks2; x1 += ks0 + 2u;                                                 \
  TF_ROUND(x0, x1, 13) TF_ROUND(x0, x1, 15) TF_ROUND(x0, x1, 26) TF_ROUND(x0, x1, 6)  \
  x0 += ks0; x1 += ks1 + 3u;                                                 \
  TF_ROUND(x0, x1, 17) TF_ROUND(x0, x1, 29) TF_ROUND(x0, x1, 16) TF_ROUND(x0, x1, 24) \
  x0 += ks1; x1 += ks2 + 4u;                                                 \
  TF_ROUND(x0, x1, 13) TF_ROUND(x0, x1, 15) TF_ROUND(x0, x1, 26) TF_ROUND(x0, x1, 6)  \
  x0 += ks2; x1 += ks0 + 5u;                                                 \
  (O0) = x0; (O1) = x1; }

static void tf_host(unsigned k0, unsigned k1, unsigned c0, unsigned c1,
                    unsigned* o0, unsigned* o1) {
  unsigned a, b;
  TF_BODY(k0, k1, c0, c1, a, b);
  *o0 = a; *o1 = b;
}

__device__ __forceinline__ void tf_dev(unsigned k0, unsigned k1, unsigned c0, unsigned c1,
                                       unsigned& o0, unsigned& o1) {
  TF_BODY(k0, k1, c0, c1, o0, o1);
}

// r(step, c) = u*2-1 from the xor-fold of threefry2x32(key_step, (0, c)) — the
// jax.random.uniform (threefry_partitionable) stream. Exact in f32.
__device__ __forceinline__ float tf_r(unsigned k0, unsigned k1, unsigned c) {
  unsigned o0, o1;
  tf_dev(k0, k1, 0u, c, o0, o1);
  const unsigned bits = o0 ^ o1;
  const float u = __uint_as_float((bits >> 9) | 0x3f800000u) - 1.0f;
  return u * 2.0f - 1.0f;
}

// ---- Tiny kernel: node -> color-group inverse map ----
__global__ __launch_bounds__(256) void build_inv(const int* __restrict__ groups,
                                                 int* __restrict__ invg) {
  const int p = blockIdx.x * 256 + threadIdx.x;
  if (p < NN) invg[groups[p]] = p / GSZ;
}

// ---- Build tables: wave-per-row, full-row register prefetch, no barriers ----
// Row p = g*GSZ + i -> node = groups[p].  prevg = (g-1) mod 8.
// pack layout per node (NPACK=36 words, zero-padded):
//   slots [0,NCOLD):       cold entries (neighbor NOT in prevg), ascending col
//   slots [NCOLD,NPACK):   hot entries (neighbor IN prevg) ascending, then cold
//                          spill (cold rank >= NCOLD), then zero padding
// word = (bf16_rne(val) << 16) | (col << 2)  (low half = LDS byte offset of m[col])
// exact8[p*DMAX + k] = {col, f32 val} ascending — exact-fallback table.
// marg[p] = 2^-9 * sum|val| + 2e-5, or 1e30 ("bad": deg>NPACK or hot>NHOT ->
//           permanent exact path; P(any bad node) ~ 4e-3 for this graph).
__global__ __launch_bounds__(256) void build_ell(const float* __restrict__ J,
                                                 const int* __restrict__ groups,
                                                 const int* __restrict__ invg,
                                                 unsigned* __restrict__ pack,
                                                 int2* __restrict__ exact8,
                                                 int* __restrict__ deg,
                                                 float* __restrict__ marg) {
  __shared__ int2 scr[4][DMAX];  // per-wave compacted (col, valbits)
  const int wv = threadIdx.x >> 6, lane = threadIdx.x & 63;
  const int p = blockIdx.x * 4 + wv;
  if (p >= NN) return;
  const int node = groups[p];
  const int prevg = (p / GSZ + NGRP - 1) % NGRP;
  const float4* row = (const float4*)(J + (size_t)node * NN);

  // Phase 1: issue ALL row loads (17 KB/wave in flight -> BW-bound, not latency)
  float4 vv[NIT];
#pragma unroll
  for (int it = 0; it < NIT; ++it) {
    const int q = it * 64 + lane;
    vv[it] = (q < NF4) ? row[q] : make_float4(0.0f, 0.0f, 0.0f, 0.0f);
  }

  // Phase 2a: ballot compaction on registers (exact ascending-column order)
  int cnt = 0;
#pragma unroll
  for (int it = 0; it < NIT; ++it) {
    const float4 v = vv[it];
    const int c0 = (it * 64 + lane) * 4;
#define COMP(X, CIDX) {                                                        \
      const bool nz = ((X) != 0.0f);                                           \
      const unsigned long long mk = __ballot(nz);                              \
      const int rk = cnt + __popcll(mk & ((1ull << lane) - 1ull));             \
      if (nz && rk < DMAX) {                                                   \
        const int2 e = make_int2((CIDX), __float_as_int(X));                   \
        exact8[(size_t)p * DMAX + rk] = e;                                     \
        scr[wv][rk] = e;                                                       \
      }                                                                        \
      cnt += __popcll(mk); }
    COMP(v.x, c0 + 0) COMP(v.y, c0 + 1) COMP(v.z, c0 + 2) COMP(v.w, c0 + 3)
#undef COMP
  }

  // Phase 2b: classify hot/cold (same wave wrote scr -> in-order DS, no barrier)
  const int cl = (cnt < DMAX) ? cnt : DMAX;
  const bool vl = (lane < cl);
  int col = 0; float val = 0.0f;
  if (vl) { const int2 e = scr[wv][lane]; col = e.x; val = __int_as_float(e.y); }
  const bool hot = vl && (invg[col] == prevg);
  const unsigned long long hm = __ballot(hot);
  const int nH = __popcll(hm);
  const int rkH = __popcll(hm & ((1ull << lane) - 1ull));
  const bool bad = (cnt > NPACK) || (nH > NHOT);
  float asum = vl ? fabsf(val) : 0.0f;

  if (!bad) {
    if (vl) {
      const int rkC = lane - rkH;  // cold rank (ranks ascending by col per class)
      const int slot = hot ? (NCOLD + rkH)
                           : ((rkC < NCOLD) ? rkC : nH + rkC);  // spill after hot
      const unsigned bits = __float_as_uint(val);
      const unsigned bf = (bits + 0x7fffu + ((bits >> 16) & 1u)) >> 16;
      pack[(size_t)p * NPACK + slot] = (bf << 16) | ((unsigned)col << 2);
    }
    const int nC = cl - nH;
    const int cend = (nC < NCOLD) ? nC : NCOLD;           // cold region fill end
    const int hend = (nC > NCOLD) ? cl : (NCOLD + nH);    // hot region fill end
    for (int k = lane; k < NPACK; k += 64)
      if ((k >= cend && k < NCOLD) || (k >= hend))
        pack[(size_t)p * NPACK + k] = 0u;                 // disjoint from value slots
  } else {
    for (int k = lane; k < NPACK; k += 64) pack[(size_t)p * NPACK + k] = 0u;
  }

  for (int s = 1; s < 64; s <<= 1) asum += __shfl_xor(asum, s, 64);
  if (lane == 0) {
    deg[p] = cl;
    marg[p] = bad ? 1e30f : (asum * 0.001953125f + 2e-5f);  // 2^-9*sum|v| + slack
  }
}

// ---- Full Gibbs chain: one workgroup per batch row (rows are independent) ----
// 576 threads = 9 waves, one node per thread per group-step.
//
// Depth-1 register pipeline (r2 post-mortem: depth-2 held 27 live uint4 ->
// compiler pinned VGPR=84 and spilled to scratch, +73MB FETCH/+48MB WRITE,
// 370us. Budget proven spill-free at 84 VGPR is 12 live uint4 — stay there.)
// r3 post-mortem: __syncthreads inside if(active)/else splits wave 8 (threads
// 533..575 inactive) -> that wave hits the barrier TWICE (exec-masked serial
// branches), skewing every later barrier pairing -> races -> absmax=2.0.
// ALL barriers must be at uniform scope. Prologue below matches r0/r2's shape.
//
// Per step s (group g), carrying only hot(s) [3 uint4] across the barrier:
//  1. issue 9 uint4 loads of words(g+1) (L2-resident table; latency hides
//     under this step's threefry + gathers)
//  2. rnext = threefry(s+1)  (dependent ~400cyc chain retires in-shadow)
//  3. hot gather from h (CRITICAL PATH: 12 slots, ~1.9 real + bcast padding)
//  4. cold pre-gather for s+1 from incoming words[0..5]: those neighbors are
//     NOT in group g, so their values during step s == values step s+1 reads
//     (group g+1 itself last written at s-7; others at <= s-1). Race-free
//     w.r.t. this step's writes by construction.
//  5. tanh + margin screen (rare f64 exact fallback), barriers, write
//  6. rotate: h = words[6..8], preSum = cold sum, rcur = rnext
__global__ __launch_bounds__(576, 3) void gibbs(const float* __restrict__ m0,
                                                const float* __restrict__ H,
                                                const int* __restrict__ groups,
                                                const unsigned* __restrict__ pack,
                                                const int2* __restrict__ exact8,
                                                const int* __restrict__ deg,
                                                const float* __restrict__ marg,
                                                float* __restrict__ out,
                                                Keys keys) {
  __shared__ float m_lds[NN];
  const int b = blockIdx.x;
  const int i = threadIdx.x;
  const bool active = (i < GSZ);

  for (int n = i; n < NN; n += 576) m_lds[n] = m0[(size_t)b * NN + n];

  // Per-thread per-group preload (step-invariant).
  int nodeg[NGRP];
  float hg[NGRP], mgg[NGRP];
  int dgg[NGRP];
  if (active) {
#pragma unroll
    for (int g = 0; g < NGRP; ++g) {
      const int p = g * GSZ + i;
      nodeg[g] = groups[p];
      hg[g] = H[nodeg[g]];
      dgg[g] = deg[p];
      mgg[g] = marg[p];
    }
  }

  const unsigned c = (unsigned)(b * GSZ + i);

  // value = high-16 bits as f32 (bf16<<16); addr = low-16 = LDS byte offset
#define MV(W)  (*(const float*)((const char*)m_lds + ((W) & 0xFFFCu)))
#define ACC4(W, A0, A1, A2, A3)                                   \
  A0 += __uint_as_float((W).x & 0xFFFF0000u) * MV((W).x);         \
  A1 += __uint_as_float((W).y & 0xFFFF0000u) * MV((W).y);         \
  A2 += __uint_as_float((W).z & 0xFFFF0000u) * MV((W).z);         \
  A3 += __uint_as_float((W).w & 0xFFFF0000u) * MV((W).w);

  // Pipeline registers: h = hot(s) [3 uint4]; preSum = cold(s); rcur = r(s).
  uint4 h0, h1, h2;
  uint4 p0, p1, p2, p3, p4, p5;
  float preSum = 0.0f, rcur = 0.0f;

  if (active) {
    const uint4* q0 = (const uint4*)(pack + (size_t)i * NPACK);  // group 0
    p0 = q0[0]; p1 = q0[1]; p2 = q0[2]; p3 = q0[3]; p4 = q0[4]; p5 = q0[5];
    h0 = q0[6]; h1 = q0[7]; h2 = q0[8];
    rcur = tf_r(keys.k0[0], keys.k1[0], c);
  }
  __syncthreads();  // m_lds ready (UNIFORM scope — see r3 post-mortem)
  if (active) {
    // Prime cold partial sum for step 0 (initial state == "values at step -1").
    float a0 = 0.0f, a1 = 0.0f, a2 = 0.0f, a3 = 0.0f;
    ACC4(p0, a0, a1, a2, a3) ACC4(p1, a0, a1, a2, a3) ACC4(p2, a0, a1, a2, a3)
    ACC4(p3, a0, a1, a2, a3) ACC4(p4, a0, a1, a2, a3) ACC4(p5, a0, a1, a2, a3)
    preSum = (a0 + a1) + (a2 + a3);
  }

#pragma unroll 1
  for (int t = 0; t < NSWEEP; ++t) {
#pragma unroll
    for (int g = 0; g < NGRP; ++g) {
      const int step = t * NGRP + g;
      float nv = 0.0f;
      uint4 n6, n7, n8;
      float rnext = 0.0f, npre = 0.0f;
      if (active) {
        // 1. Issue next group's 9-word load (independent; waits land at step 4)
        const int gn = (g + 1) & (NGRP - 1);
        const uint4* qn = (const uint4*)(pack + (size_t)(gn * GSZ + i) * NPACK);
        const uint4 n0 = qn[0], n1 = qn[1], n2 = qn[2];
        const uint4 n3 = qn[3], n4 = qn[4], n5 = qn[5];
        n6 = qn[6]; n7 = qn[7]; n8 = qn[8];

        // 2. Next step's threefry: retires under this step's gathers.
        const int sn = (step + 1 < NSTEP) ? step + 1 : step;
        rnext = tf_r(keys.k0[sn], keys.k1[sn], c);

        // 3. Hot gather (critical path): 12 slots, padding reads m_lds[0].
        float a0 = 0.0f, a1 = 0.0f, a2 = 0.0f, a3 = 0.0f;
        ACC4(h0, a0, a1, a2, a3) ACC4(h1, a0, a1, a2, a3) ACC4(h2, a0, a1, a2, a3)

        // 4. Cold pre-gather for step s+1 (addresses exclude group g -> safe
        //    to read before/during this step's writes).
        float b0 = 0.0f, b1 = 0.0f, b2 = 0.0f, b3 = 0.0f;
        ACC4(n0, b0, b1, b2, b3) ACC4(n1, b0, b1, b2, b3) ACC4(n2, b0, b1, b2, b3)
        ACC4(n3, b0, b1, b2, b3) ACC4(n4, b0, b1, b2, b3) ACC4(n5, b0, b1, b2, b3)
        npre = (b0 + b1) + (b2 + b3);

        // 5. Screen + decide.
        const float I = preSum + ((a0 + a1) + (a2 + a3)) + hg[g];
        const float th = tanhf(I);
        const float d = th - rcur;
        if (__builtin_expect(fabsf(d) > mgg[g], 1)) {
          // |tanhf(I_fast) - tanh64(I_exact)| <= marg -> sign matches exact
          nv = (d > 0.0f) ? 1.0f : -1.0f;
        } else {
          // Boundary-close (or bad node): settle in f64 from exact f32 table.
          const int dg = dgg[g];
          const int2* ep = exact8 + (size_t)(g * GSZ + i) * DMAX;
          double I64 = (double)hg[g];
          for (int k = 0; k < dg; ++k) {
            const int2 e = ep[k];
            I64 += (double)__int_as_float(e.y) * (double)m_lds[e.x];
          }
          const double diff = tanh(I64) - (double)rcur;
          nv = (diff > 0.0) ? 1.0f : ((diff < 0.0) ? -1.0f : 0.0f);
        }
      }
      __syncthreads();                  // all gathers done (uniform)
      if (active) m_lds[nodeg[g]] = nv; // compute-all-then-set semantics
      __syncthreads();                  // scatter visible before next hot gather
      if (active) {
        preSum = npre; rcur = rnext;
        h0 = n6; h1 = n7; h2 = n8;      // hot(s+1) carried from incoming words
      }
    }
  }

  for (int n = i; n < NN; n += 576) out[(size_t)b * NN + n] = m_lds[n];
#undef ACC4
#undef MV
}

extern "C" void kernel_launch(void* const* d_in, const int* in_sizes, int n_in,
                              void* d_out, int out_size, void* d_ws, size_t ws_size,
                              hipStream_t stream) {
  const float* m0     = (const float*)d_in[0];
  const float* J      = (const float*)d_in[1];
  const float* H      = (const float*)d_in[2];
  const int*   groups = (const int*)d_in[3];
  // d_in[4] = sample_num (=10, hardcoded as NSWEEP)

  // Workspace: pack[NN*NPACK] u32 (614 KB) | exact8[NN*DMAX] int2 (1.64 MB)
  //          | deg[NN] i32 | marg[NN] f32 | invg[NN] i32   -> ~2.30 MB total
  char* ws = (char*)d_ws;
  unsigned* pack   = (unsigned*)ws;                     ws += (size_t)NN * NPACK * 4;
  int2*     exact8 = (int2*)ws;                         ws += (size_t)NN * DMAX * 8;
  int*      deg    = (int*)ws;                          ws += (size_t)NN * 4;
  float*    marg   = (float*)ws;                        ws += (size_t)NN * 4;
  int*      invg   = (int*)ws;

  // Host-side key schedule, jax_threefry_partitionable=True (fold-like split):
  // key(42) -> (0, 42); split(key, n)[i] = threefry2x32(key, (0, i)).
  Keys keys;
  for (int t = 0; t < NSWEEP; ++t) {
    unsigned ik0, ik1;
    tf_host(0u, 42u, 0u, (unsigned)t, &ik0, &ik1);
    for (int g = 0; g < NGRP; ++g) {
      unsigned gk0, gk1;
      tf_host(ik0, ik1, 0u, (unsigned)g, &gk0, &gk1);
      keys.k0[t * NGRP + g] = gk0;
      keys.k1[t * NGRP + g] = gk1;
    }
  }

  build_inv<<<(NN + 255) / 256, 256, 0, stream>>>(groups, invg);
  build_ell<<<(NN + 3) / 4, 256, 0, stream>>>(J, groups, invg, pack, exact8, deg, marg);
  gibbs<<<BB, 576, 0, stream>>>(m0, H, groups, pack, exact8, deg, marg,
                                (float*)d_out, keys);
}